// Round 2
// baseline (16440.106 us; speedup 1.0000x reference)
//
#include <hip/hip_runtime.h>
#include <stdint.h>

typedef short  s8v  __attribute__((ext_vector_type(8)));
typedef float  f4v  __attribute__((ext_vector_type(4)));
typedef float  f2v  __attribute__((ext_vector_type(2)));
typedef int    i4v  __attribute__((ext_vector_type(4)));
typedef unsigned short us4 __attribute__((ext_vector_type(4)));

#define MFMA16(a,b,c) __builtin_amdgcn_mfma_f32_16x16x32_bf16(a,b,c,0,0,0)

#define K1 1.44269504088896340f   /* log2(e)   */
#define K2 2.88539008177792681f   /* 2*log2(e) */

__device__ __forceinline__ unsigned short f2bf(float f) {
  union { float f; uint32_t u; } v; v.f = f;
  return (unsigned short)((v.u + 0x7FFFu + ((v.u >> 16) & 1u)) >> 16);
}
__device__ __forceinline__ float bflo(uint32_t dw) {
  union { uint32_t u; float f; } v; v.u = dw << 16; return v.f;
}
__device__ __forceinline__ float bfhi(uint32_t dw) {
  union { uint32_t u; float f; } v; v.u = dw & 0xFFFF0000u; return v.f;
}
__device__ __forceinline__ float bfu(unsigned short u) {
  union { uint32_t u; float f; } v; v.u = ((uint32_t)u) << 16; return v.f;
}

// ---------------- prep: convert weights to bf16, sum biases ----------------
__global__ __launch_bounds__(256) void prep_kernel(
    const float* __restrict__ We, const float* __restrict__ Ue,
    const float* __restrict__ Wih, const float* __restrict__ Whh,
    const float* __restrict__ bih, const float* __restrict__ bhh,
    unsigned short* __restrict__ Wih_b, unsigned short* __restrict__ Whh_b,
    unsigned short* __restrict__ We_b, unsigned short* __restrict__ Ue_b,
    float* __restrict__ bsum)
{
  int i0 = blockIdx.x * 256 + threadIdx.x;
  int stride = gridDim.x * 256;
  for (int i = i0; i < 262144; i += stride) Wih_b[i] = f2bf(Wih[i]);
  for (int i = i0; i < 262144; i += stride) Whh_b[i] = f2bf(Whh[i]);
  for (int i = i0; i < 65536;  i += stride) We_b[i]  = f2bf(We[i]);
  for (int i = i0; i < 16384;  i += stride) Ue_b[i]  = f2bf(Ue[i]);
  for (int i = i0; i < 1024;   i += stride) bsum[i]  = bih[i] + bhh[i];
}

// ---- Ux GEMM: UxK8[b][tg][n][16] = fp8(K2 * sum_t x[b][t][n]*U_e[s][t]) ----
// layout: b*2048 + tg*256 + n  (16-byte units, 16 t per chunk)
__global__ __launch_bounds__(256) void ux_kernel(
    const float* __restrict__ x, const unsigned short* __restrict__ Ue_b,
    unsigned char* __restrict__ UxK8)
{
  __shared__ unsigned short xT[64 * 136];  // x[b][t][n] -> [n][t], padded
  __shared__ unsigned short oT[64 * 136];  // result rows n, cols s (bf16)
  const int tid = threadIdx.x;
  const int b   = blockIdx.x >> 2;
  const int n0  = (blockIdx.x & 3) * 64;

  {
    const int nl = tid & 63, tp = tid >> 6;
    for (int i = 0; i < 32; i++) {
      int t = tp + i * 4;
      xT[nl * 136 + t] = f2bf(x[((size_t)b * 128 + t) * 256 + n0 + nl]);
    }
  }
  __syncthreads();
  {
    const int w = tid >> 6, lane = tid & 63;
    const int l15 = lane & 15, quad = lane >> 4;
    for (int tt = 0; tt < 8; tt++) {
      f4v acc = {0.f, 0.f, 0.f, 0.f};
      #pragma unroll
      for (int kt = 0; kt < 4; kt++) {
        s8v a  = *(const s8v*)&xT[(w * 16 + l15) * 136 + kt * 32 + quad * 8];
        s8v bb = *(const s8v*)&Ue_b[(tt * 16 + l15) * 128 + kt * 32 + quad * 8];
        acc = MFMA16(a, bb, acc);
      }
      #pragma unroll
      for (int r = 0; r < 4; r++)
        oT[(w * 16 + quad * 4 + r) * 136 + tt * 16 + l15] = f2bf(acc[r] * K2);
    }
  }
  __syncthreads();
  {
    for (int p = 0; p < 2; p++) {
      int row = (tid >> 3) + p * 32;   // local n
      int tg  = tid & 7;               // 16-t chunk
      const unsigned int* sp = (const unsigned int*)&oT[row * 136 + tg * 16];
      i4v outv;
      #pragma unroll
      for (int j = 0; j < 4; j++) {
        unsigned int d0 = sp[2 * j], d1 = sp[2 * j + 1];
        int w = __builtin_amdgcn_cvt_pk_fp8_f32(bflo(d0), bfhi(d0), 0, 0);
        w     = __builtin_amdgcn_cvt_pk_fp8_f32(bflo(d1), bfhi(d1), w, 1);
        outv[j] = w;
      }
      *(i4v*)&UxK8[(((size_t)b * 8 + tg) * 256 + n0 + row) * 16] = outv;
    }
  }
}

// ---------------- persistent recurrence: 256 blocks x 1024 thr, 8 batch/blk --
__global__ __launch_bounds__(1024, 4) void rnn_kernel(
    const unsigned char* __restrict__ UxK8,
    const unsigned short* __restrict__ We_b,
    const unsigned short* __restrict__ Wih_b,
    const unsigned short* __restrict__ Whh_b,
    const float* __restrict__ bsum_g,
    const float* __restrict__ Ve,
    float* __restrict__ out)
{
  __shared__ unsigned short h_hist[2048 * 20];  // 80 KB: bf16 h, depth 16, stride 20
  __shared__ unsigned short xt_b[16 * 264];     // bf16, rows 8..15 zero-pad
  __shared__ unsigned short h_b [16 * 264];
  __shared__ unsigned short c_b [16 * 264];
  __shared__ float  c_f[8 * 256];               // f32 cell state
  __shared__ float  e_f[8 * 256];
  __shared__ float  wv_lds[8 * 128 * 2];        // [b][t] -> (K2*whs, -2*V)
  __shared__ float  bsum[1024];
  __shared__ float  Zpart[8][4];

  const int tid  = threadIdx.x;
  const int wv   = tid >> 6;
  const int lane = tid & 63;
  const int l15  = lane & 15;
  const int quad = lane >> 4;
  const int blk  = blockIdx.x;

  for (int i = tid; i < 16 * 264; i += 1024) { xt_b[i] = 0; h_b[i] = 0; c_b[i] = 0; }
  for (int i = tid; i < 2048; i += 1024) c_f[i] = 0.f;
  bsum[tid] = bsum_g[tid];
  {
    int b8 = tid >> 7, t = tid & 127;
    wv_lds[(b8 * 128 + t) * 2 + 1] = -2.0f * Ve[t];
    wv_lds[(b8 * 128 + t) * 2 + 0] = 0.f;
  }
  float Vs = 0.f;
  for (int t = 0; t < 128; t++) Vs += Ve[t];
  __syncthreads();

  const int an = tid & 255;   // n index owned by this thread
  const int bq = tid >> 8;    // handles batches bq and bq+4

  const i4v* ub = (const i4v*)UxK8;
  const size_t ux_base0 = ((size_t)(blk * 8 + bq)    ) * 2048 + an;
  const size_t ux_base1 = ((size_t)(blk * 8 + bq + 4)) * 2048 + an;

  f4v ga0, ga1, ga2, ga3;

  for (int s = 0; s < 128; s++) {
    __syncthreads();   // B1: h_b/c_b stable from previous step

    // ---- whs = [h,c] @ W_e.T  (waves 0..7, t-tile = wv) ----
    if (wv < 8) {
      f4v acc = {0.f, 0.f, 0.f, 0.f};
      #pragma unroll
      for (int kt = 0; kt < 8; kt++) {
        s8v a  = *(const s8v*)&h_b[l15 * 264 + kt * 32 + quad * 8];
        s8v bb = *(const s8v*)&We_b[(wv * 16 + l15) * 512 + kt * 32 + quad * 8];
        acc = MFMA16(a, bb, acc);
      }
      #pragma unroll
      for (int kt = 0; kt < 8; kt++) {
        s8v a  = *(const s8v*)&c_b[l15 * 264 + kt * 32 + quad * 8];
        s8v bb = *(const s8v*)&We_b[(wv * 16 + l15) * 512 + 256 + kt * 32 + quad * 8];
        acc = MFMA16(a, bb, acc);
      }
      if (lane < 32) {
        #pragma unroll
        for (int r = 0; r < 4; r++)
          wv_lds[((quad * 4 + r) * 128 + wv * 16 + l15) * 2] = K2 * acc[r];
      }
    }
    __syncthreads();   // B2: whsK ready

    // ---- prefetch pass-0 UxK (nontemporal: don't evict weights from L2) ----
    i4v d0[8];
    #pragma unroll
    for (int tg = 0; tg < 8; tg++)
      d0[tg] = __builtin_nontemporal_load(ub + ux_base0 + tg * 256);

    // ---- h-part of gates (all 16 waves), kt-paired for load depth ----
    ga0 = (f4v){0.f,0.f,0.f,0.f}; ga1 = ga0; ga2 = ga0; ga3 = ga0;
    #pragma unroll
    for (int kp = 0; kp < 4; kp++) {
      const int k0 = kp * 2, k1 = kp * 2 + 1;
      s8v aA = *(const s8v*)&h_b[l15 * 264 + k0 * 32 + quad * 8];
      s8v aB = *(const s8v*)&h_b[l15 * 264 + k1 * 32 + quad * 8];
      const int r0 = (wv * 16 + l15) * 256;
      s8v b00 = *(const s8v*)&Whh_b[(size_t)(     0 + r0) + k0 * 32 + quad * 8];
      s8v b01 = *(const s8v*)&Whh_b[(size_t)( 65536 + r0) + k0 * 32 + quad * 8];
      s8v b02 = *(const s8v*)&Whh_b[(size_t)(131072 + r0) + k0 * 32 + quad * 8];
      s8v b03 = *(const s8v*)&Whh_b[(size_t)(196608 + r0) + k0 * 32 + quad * 8];
      s8v b10 = *(const s8v*)&Whh_b[(size_t)(     0 + r0) + k1 * 32 + quad * 8];
      s8v b11 = *(const s8v*)&Whh_b[(size_t)( 65536 + r0) + k1 * 32 + quad * 8];
      s8v b12 = *(const s8v*)&Whh_b[(size_t)(131072 + r0) + k1 * 32 + quad * 8];
      s8v b13 = *(const s8v*)&Whh_b[(size_t)(196608 + r0) + k1 * 32 + quad * 8];
      ga0 = MFMA16(aA, b00, ga0); ga1 = MFMA16(aA, b01, ga1);
      ga2 = MFMA16(aA, b02, ga2); ga3 = MFMA16(aA, b03, ga3);
      ga0 = MFMA16(aB, b10, ga0); ga1 = MFMA16(aB, b11, ga1);
      ga2 = MFMA16(aB, b12, ga2); ga3 = MFMA16(aB, b13, ga3);
    }

    // ---- attention: e[b][n] = Vs + sum_t (-2 V[t]) / (exp2(UxK+whsK)+1) ----
    {
      i4v d1[8];
      #pragma unroll
      for (int tg = 0; tg < 8; tg++)
        d1[tg] = __builtin_nontemporal_load(ub + ux_base1 + tg * 256);

      #pragma unroll
      for (int pass = 0; pass < 2; pass++) {
        const int bb8 = bq + pass * 4;
        const f4v* wvf = (const f4v*)&wv_lds[bb8 * 256];
        float a0 = 0.f, a1 = 0.f, a2 = 0.f, a3 = 0.f;
        #pragma unroll
        for (int tg = 0; tg < 8; tg++) {
          i4v d = pass ? d1[tg] : d0[tg];
          #pragma unroll
          for (int q = 0; q < 4; q++) {
            uint32_t dw = (uint32_t)d[q];
            f2v lo = __builtin_amdgcn_cvt_pk_f32_fp8(dw, 0);
            f2v hi = __builtin_amdgcn_cvt_pk_f32_fp8(dw, 1);
            const int t = tg * 16 + q * 4;
            f4v w01 = wvf[(t >> 1)];       // (whs_t, -2V_t, whs_t+1, -2V_t+1)
            f4v w23 = wvf[(t >> 1) + 1];
            float x0 = lo.x + w01.x;
            a0 = fmaf(w01.y, __builtin_amdgcn_rcpf(__builtin_amdgcn_exp2f(x0) + 1.0f), a0);
            float x1 = lo.y + w01.z;
            a1 = fmaf(w01.w, __builtin_amdgcn_rcpf(__builtin_amdgcn_exp2f(x1) + 1.0f), a1);
            float x2 = hi.x + w23.x;
            a2 = fmaf(w23.y, __builtin_amdgcn_rcpf(__builtin_amdgcn_exp2f(x2) + 1.0f), a2);
            float x3 = hi.y + w23.z;
            a3 = fmaf(w23.w, __builtin_amdgcn_rcpf(__builtin_amdgcn_exp2f(x3) + 1.0f), a3);
          }
        }
        float e = Vs + ((a0 + a1) + (a2 + a3));
        e_f[bb8 * 256 + an] = e;
        float pe = __builtin_amdgcn_exp2f(K1 * e);
        #pragma unroll
        for (int off = 32; off >= 1; off >>= 1) pe += __shfl_xor(pe, off);
        if (lane == 0) Zpart[bb8][wv & 3] = pe;
      }
    }
    __syncthreads();  // B3: e_f + Zpart ready

    // ---- softmax redistribution + xt (bf16) ----
    {
      const int b8s = tid >> 7;
      const int nn0 = (tid & 127) * 2;
      f4v zp = *(const f4v*)&Zpart[b8s][0];
      float zi = 1.0f / ((zp.x + zp.y) + (zp.z + zp.w));
      float2 ee = *(const float2*)&e_f[b8s * 256 + nn0];
      float p0 = __builtin_amdgcn_exp2f(K1 * ee.x);
      float p1 = __builtin_amdgcn_exp2f(K1 * ee.y);
      unsigned int packed = (unsigned int)f2bf(p0 * zi * ee.x)
                          | ((unsigned int)f2bf(p1 * zi * ee.y) << 16);
      *(unsigned int*)&xt_b[b8s * 264 + nn0] = packed;
    }
    __syncthreads();  // B4: xt ready

    // ---- xt-part of gates ----
    #pragma unroll
    for (int kp = 0; kp < 4; kp++) {
      const int k0 = kp * 2, k1 = kp * 2 + 1;
      s8v aA = *(const s8v*)&xt_b[l15 * 264 + k0 * 32 + quad * 8];
      s8v aB = *(const s8v*)&xt_b[l15 * 264 + k1 * 32 + quad * 8];
      const int r0 = (wv * 16 + l15) * 256;
      s8v b00 = *(const s8v*)&Wih_b[(size_t)(     0 + r0) + k0 * 32 + quad * 8];
      s8v b01 = *(const s8v*)&Wih_b[(size_t)( 65536 + r0) + k0 * 32 + quad * 8];
      s8v b02 = *(const s8v*)&Wih_b[(size_t)(131072 + r0) + k0 * 32 + quad * 8];
      s8v b03 = *(const s8v*)&Wih_b[(size_t)(196608 + r0) + k0 * 32 + quad * 8];
      s8v b10 = *(const s8v*)&Wih_b[(size_t)(     0 + r0) + k1 * 32 + quad * 8];
      s8v b11 = *(const s8v*)&Wih_b[(size_t)( 65536 + r0) + k1 * 32 + quad * 8];
      s8v b12 = *(const s8v*)&Wih_b[(size_t)(131072 + r0) + k1 * 32 + quad * 8];
      s8v b13 = *(const s8v*)&Wih_b[(size_t)(196608 + r0) + k1 * 32 + quad * 8];
      ga0 = MFMA16(aA, b00, ga0); ga1 = MFMA16(aA, b01, ga1);
      ga2 = MFMA16(aA, b02, ga2); ga3 = MFMA16(aA, b03, ga3);
      ga0 = MFMA16(aB, b10, ga0); ga1 = MFMA16(aB, b11, ga1);
      ga2 = MFMA16(aB, b12, ga2); ga3 = MFMA16(aB, b13, ga3);
    }

    // ---- pointwise LSTM straight from accumulators (lanes 0..31) ----
    if (lane < 32) {
      const int jj = wv * 16 + l15;
      #pragma unroll
      for (int r = 0; r < 4; r++) {
        const int m = quad * 4 + r;
        float iG = ga0[r] + bsum[jj];
        float fG = ga1[r] + bsum[256 + jj];
        float gG = ga2[r] + bsum[512 + jj];
        float oG = ga3[r] + bsum[768 + jj];
        float si = __builtin_amdgcn_rcpf(1.0f + __builtin_amdgcn_exp2f(-K1 * iG));
        float sf = __builtin_amdgcn_rcpf(1.0f + __builtin_amdgcn_exp2f(-K1 * fG));
        float so = __builtin_amdgcn_rcpf(1.0f + __builtin_amdgcn_exp2f(-K1 * oG));
        float tg_ = 1.0f - 2.0f * __builtin_amdgcn_rcpf(1.0f + __builtin_amdgcn_exp2f(K2 * gG));
        float cn = sf * c_f[m * 256 + jj] + si * tg_;
        float th = 1.0f - 2.0f * __builtin_amdgcn_rcpf(1.0f + __builtin_amdgcn_exp2f(K2 * cn));
        float hn = so * th;
        c_f[m * 256 + jj] = cn;
        c_b[m * 264 + jj] = f2bf(cn);
        h_b[m * 264 + jj] = f2bf(hn);
        h_hist[(m * 256 + jj) * 20 + (s & 15)] = f2bf(hn);
      }
    }

    // ---- full-line coalesced output dump every 16 steps ----
    if ((s & 15) == 15) {
      __syncthreads();
      #pragma unroll
      for (int p = 0; p < 2; p++) {
        int rid = p * 1024 + tid;
        int mB = rid >> 8, j = rid & 255;
        const us4* hp = (const us4*)&h_hist[rid * 20];
        float* dst = &out[(((size_t)blk * 8 + mB) * 256 + j) * 128 + (s - 15)];
        #pragma unroll
        for (int c = 0; c < 4; c++) {
          us4 u = hp[c];
          f4v o = { bfu(u.x), bfu(u.y), bfu(u.z), bfu(u.w) };
          __builtin_nontemporal_store(o, (f4v*)(dst + c * 4));
        }
      }
    }
  }
}

extern "C" void kernel_launch(void* const* d_in, const int* in_sizes, int n_in,
                              void* d_out, int out_size, void* d_ws, size_t ws_size,
                              hipStream_t stream) {
  const float* x   = (const float*)d_in[0];
  const float* We  = (const float*)d_in[1];
  const float* Ue  = (const float*)d_in[2];
  const float* Ve  = (const float*)d_in[3];
  const float* Wih = (const float*)d_in[4];
  const float* Whh = (const float*)d_in[5];
  const float* bih = (const float*)d_in[6];
  const float* bhh = (const float*)d_in[7];
  float* out = (float*)d_out;

  char* p = (char*)d_ws;
  unsigned char*  UxK8  = (unsigned char*)p;  p += (size_t)67108864; // 2048*256*128 fp8
  unsigned short* Wih_b = (unsigned short*)p; p += 524288;
  unsigned short* Whh_b = (unsigned short*)p; p += 524288;
  unsigned short* We_b  = (unsigned short*)p; p += 131072;
  unsigned short* Ue_b  = (unsigned short*)p; p += 32768;
  float* bsum = (float*)p;

  prep_kernel<<<512, 256, 0, stream>>>(We, Ue, Wih, Whh, bih, bhh,
                                       Wih_b, Whh_b, We_b, Ue_b, bsum);
  ux_kernel<<<8192, 256, 0, stream>>>(x, Ue_b, UxK8);
  rnn_kernel<<<256, 1024, 0, stream>>>(UxK8, We_b, Wih_b, Whh_b, bsum, Ve, out);
}

// Round 3
// 10261.918 us; speedup vs baseline: 1.6021x; 1.6021x over previous
//
#include <hip/hip_runtime.h>
#include <stdint.h>

typedef short  s8v  __attribute__((ext_vector_type(8)));
typedef float  f4v  __attribute__((ext_vector_type(4)));
typedef float  f2v  __attribute__((ext_vector_type(2)));
typedef int    i4v  __attribute__((ext_vector_type(4)));
typedef unsigned short us4 __attribute__((ext_vector_type(4)));

#define MFMA16(a,b,c) __builtin_amdgcn_mfma_f32_16x16x32_bf16(a,b,c,0,0,0)

#define K1 1.44269504088896340f   /* log2(e)   */
#define K2 2.88539008177792681f   /* 2*log2(e) */

__device__ __forceinline__ unsigned short f2bf(float f) {
  union { float f; uint32_t u; } v; v.f = f;
  return (unsigned short)((v.u + 0x7FFFu + ((v.u >> 16) & 1u)) >> 16);
}
__device__ __forceinline__ float bflo(uint32_t dw) {
  union { uint32_t u; float f; } v; v.u = dw << 16; return v.f;
}
__device__ __forceinline__ float bfhi(uint32_t dw) {
  union { uint32_t u; float f; } v; v.u = dw & 0xFFFF0000u; return v.f;
}
__device__ __forceinline__ float bfu(unsigned short u) {
  union { uint32_t u; float f; } v; v.u = ((uint32_t)u) << 16; return v.f;
}

// ---------------- prep: convert weights to bf16, sum biases ----------------
__global__ __launch_bounds__(256) void prep_kernel(
    const float* __restrict__ We, const float* __restrict__ Ue,
    const float* __restrict__ Wih, const float* __restrict__ Whh,
    const float* __restrict__ bih, const float* __restrict__ bhh,
    unsigned short* __restrict__ Wih_b, unsigned short* __restrict__ Whh_b,
    unsigned short* __restrict__ We_b, unsigned short* __restrict__ Ue_b,
    float* __restrict__ bsum)
{
  int i0 = blockIdx.x * 256 + threadIdx.x;
  int stride = gridDim.x * 256;
  for (int i = i0; i < 262144; i += stride) Wih_b[i] = f2bf(Wih[i]);
  for (int i = i0; i < 262144; i += stride) Whh_b[i] = f2bf(Whh[i]);
  for (int i = i0; i < 65536;  i += stride) We_b[i]  = f2bf(We[i]);
  for (int i = i0; i < 16384;  i += stride) Ue_b[i]  = f2bf(Ue[i]);
  for (int i = i0; i < 1024;   i += stride) bsum[i]  = bih[i] + bhh[i];
}

// ---- Ux GEMM: UxK8[b][tg][n][16] = fp8(K2 * sum_t x[b][t][n]*U_e[s][t]) ----
// layout: b*2048 + tg*256 + n  (16-byte units, 16 t per chunk)
__global__ __launch_bounds__(256) void ux_kernel(
    const float* __restrict__ x, const unsigned short* __restrict__ Ue_b,
    unsigned char* __restrict__ UxK8)
{
  __shared__ unsigned short xT[64 * 136];  // x[b][t][n] -> [n][t], padded
  __shared__ unsigned short oT[64 * 136];  // result rows n, cols s (bf16)
  const int tid = threadIdx.x;
  const int b   = blockIdx.x >> 2;
  const int n0  = (blockIdx.x & 3) * 64;

  {
    const int nl = tid & 63, tp = tid >> 6;
    for (int i = 0; i < 32; i++) {
      int t = tp + i * 4;
      xT[nl * 136 + t] = f2bf(x[((size_t)b * 128 + t) * 256 + n0 + nl]);
    }
  }
  __syncthreads();
  {
    const int w = tid >> 6, lane = tid & 63;
    const int l15 = lane & 15, quad = lane >> 4;
    for (int tt = 0; tt < 8; tt++) {
      f4v acc = {0.f, 0.f, 0.f, 0.f};
      #pragma unroll
      for (int kt = 0; kt < 4; kt++) {
        s8v a  = *(const s8v*)&xT[(w * 16 + l15) * 136 + kt * 32 + quad * 8];
        s8v bb = *(const s8v*)&Ue_b[(tt * 16 + l15) * 128 + kt * 32 + quad * 8];
        acc = MFMA16(a, bb, acc);
      }
      #pragma unroll
      for (int r = 0; r < 4; r++)
        oT[(w * 16 + quad * 4 + r) * 136 + tt * 16 + l15] = f2bf(acc[r] * K2);
    }
  }
  __syncthreads();
  {
    for (int p = 0; p < 2; p++) {
      int row = (tid >> 3) + p * 32;   // local n
      int tg  = tid & 7;               // 16-t chunk
      const unsigned int* sp = (const unsigned int*)&oT[row * 136 + tg * 16];
      i4v outv;
      #pragma unroll
      for (int j = 0; j < 4; j++) {
        unsigned int d0 = sp[2 * j], d1 = sp[2 * j + 1];
        int w = __builtin_amdgcn_cvt_pk_fp8_f32(bflo(d0), bfhi(d0), 0, 0);
        w     = __builtin_amdgcn_cvt_pk_fp8_f32(bflo(d1), bfhi(d1), w, 1);
        outv[j] = w;
      }
      *(i4v*)&UxK8[(((size_t)b * 8 + tg) * 256 + n0 + row) * 16] = outv;
    }
  }
}

// ---------------- persistent recurrence: 256 blocks x 1024 thr, 8 batch/blk --
__global__ __launch_bounds__(1024, 4) void rnn_kernel(
    const unsigned char* __restrict__ UxK8,
    const unsigned short* __restrict__ We_b,
    const unsigned short* __restrict__ Wih_b,
    const unsigned short* __restrict__ Whh_b,
    const float* __restrict__ bsum_g,
    const float* __restrict__ Ve,
    float* __restrict__ out)
{
  __shared__ unsigned short h_hist[2048 * 20];  // 80 KB: bf16 h, depth 16, stride 20
  __shared__ unsigned short xt_b[16 * 264];     // bf16, rows 8..15 zero-pad
  __shared__ unsigned short h_b [16 * 264];
  __shared__ unsigned short c_b [16 * 264];
  __shared__ float  c_f[8 * 256];               // f32 cell state
  __shared__ float  e_f[8 * 256];
  __shared__ float  wv_lds[8 * 128 * 2];        // [b][t] -> (K2*whs, -2*V)
  __shared__ float  bsum[1024];
  __shared__ float  Zpart[8][4];

  const int tid  = threadIdx.x;
  const int wv   = tid >> 6;
  const int lane = tid & 63;
  const int l15  = lane & 15;
  const int quad = lane >> 4;
  const int blk  = blockIdx.x;

  for (int i = tid; i < 16 * 264; i += 1024) { xt_b[i] = 0; h_b[i] = 0; c_b[i] = 0; }
  for (int i = tid; i < 2048; i += 1024) c_f[i] = 0.f;
  bsum[tid] = bsum_g[tid];
  {
    int b8 = tid >> 7, t = tid & 127;
    wv_lds[(b8 * 128 + t) * 2 + 1] = -2.0f * Ve[t];
    wv_lds[(b8 * 128 + t) * 2 + 0] = 0.f;
  }
  float Vs = 0.f;
  for (int t = 0; t < 128; t++) Vs += Ve[t];
  __syncthreads();

  const int an = tid & 255;   // n index owned by this thread
  const int bq = tid >> 8;    // handles batches bq and bq+4

  const i4v* ub = (const i4v*)UxK8;
  const size_t ux_base0 = ((size_t)(blk * 8 + bq)    ) * 2048 + an;
  const size_t ux_base1 = ((size_t)(blk * 8 + bq + 4)) * 2048 + an;

  f4v ga0, ga1, ga2, ga3;

  for (int s = 0; s < 128; s++) {
    __syncthreads();   // B1: h_b/c_b stable from previous step

    // ---- whs = [h,c] @ W_e.T  (waves 0..7, t-tile = wv) ----
    if (wv < 8) {
      f4v acc = {0.f, 0.f, 0.f, 0.f};
      #pragma unroll
      for (int kt = 0; kt < 8; kt++) {
        s8v a  = *(const s8v*)&h_b[l15 * 264 + kt * 32 + quad * 8];
        s8v bb = *(const s8v*)&We_b[(wv * 16 + l15) * 512 + kt * 32 + quad * 8];
        acc = MFMA16(a, bb, acc);
      }
      #pragma unroll
      for (int kt = 0; kt < 8; kt++) {
        s8v a  = *(const s8v*)&c_b[l15 * 264 + kt * 32 + quad * 8];
        s8v bb = *(const s8v*)&We_b[(wv * 16 + l15) * 512 + 256 + kt * 32 + quad * 8];
        acc = MFMA16(a, bb, acc);
      }
      if (lane < 32) {
        #pragma unroll
        for (int r = 0; r < 4; r++)
          wv_lds[((quad * 4 + r) * 128 + wv * 16 + l15) * 2] = K2 * acc[r];
      }
    }
    __syncthreads();   // B2: whsK ready

    // ---- h-part of gates (all 16 waves), kt-paired for load depth ----
    ga0 = (f4v){0.f,0.f,0.f,0.f}; ga1 = ga0; ga2 = ga0; ga3 = ga0;
    #pragma unroll
    for (int kp = 0; kp < 4; kp++) {
      const int k0 = kp * 2, k1 = kp * 2 + 1;
      s8v aA = *(const s8v*)&h_b[l15 * 264 + k0 * 32 + quad * 8];
      s8v aB = *(const s8v*)&h_b[l15 * 264 + k1 * 32 + quad * 8];
      const int r0 = (wv * 16 + l15) * 256;
      s8v b00 = *(const s8v*)&Whh_b[(size_t)(     0 + r0) + k0 * 32 + quad * 8];
      s8v b01 = *(const s8v*)&Whh_b[(size_t)( 65536 + r0) + k0 * 32 + quad * 8];
      s8v b02 = *(const s8v*)&Whh_b[(size_t)(131072 + r0) + k0 * 32 + quad * 8];
      s8v b03 = *(const s8v*)&Whh_b[(size_t)(196608 + r0) + k0 * 32 + quad * 8];
      s8v b10 = *(const s8v*)&Whh_b[(size_t)(     0 + r0) + k1 * 32 + quad * 8];
      s8v b11 = *(const s8v*)&Whh_b[(size_t)( 65536 + r0) + k1 * 32 + quad * 8];
      s8v b12 = *(const s8v*)&Whh_b[(size_t)(131072 + r0) + k1 * 32 + quad * 8];
      s8v b13 = *(const s8v*)&Whh_b[(size_t)(196608 + r0) + k1 * 32 + quad * 8];
      ga0 = MFMA16(aA, b00, ga0); ga1 = MFMA16(aA, b01, ga1);
      ga2 = MFMA16(aA, b02, ga2); ga3 = MFMA16(aA, b03, ga3);
      ga0 = MFMA16(aB, b10, ga0); ga1 = MFMA16(aB, b11, ga1);
      ga2 = MFMA16(aB, b12, ga2); ga3 = MFMA16(aB, b13, ga3);
    }

    // ---- attention: e[b][n] = Vs + sum_t (-2 V[t]) / (exp2(UxK+whsK)+1) ----
    // Plain (L3-allocating) loads: 67 MB UxK is re-referenced every step and
    // must stay Infinity-Cache-resident. Rolling 1-deep prefetch, no arrays.
    #pragma unroll
    for (int pass = 0; pass < 2; pass++) {
      const int bb8 = bq + pass * 4;
      const size_t base = pass ? ux_base1 : ux_base0;
      const f4v* wvf = (const f4v*)&wv_lds[bb8 * 256];
      float a0 = 0.f, a1 = 0.f, a2 = 0.f, a3 = 0.f;
      i4v cur = ub[base];
      #pragma unroll 2
      for (int tg = 0; tg < 8; tg++) {
        i4v nxt = (tg < 7) ? ub[base + (size_t)(tg + 1) * 256] : cur;
        #pragma unroll
        for (int q = 0; q < 4; q++) {
          uint32_t dw = (uint32_t)cur[q];
          f2v lo = __builtin_amdgcn_cvt_pk_f32_fp8(dw, 0);
          f2v hi = __builtin_amdgcn_cvt_pk_f32_fp8(dw, 1);
          const int t = tg * 16 + q * 4;
          f4v w01 = wvf[(t >> 1)];       // (whs_t, -2V_t, whs_t+1, -2V_t+1)
          f4v w23 = wvf[(t >> 1) + 1];
          float x0 = lo.x + w01.x;
          a0 = fmaf(w01.y, __builtin_amdgcn_rcpf(__builtin_amdgcn_exp2f(x0) + 1.0f), a0);
          float x1 = lo.y + w01.z;
          a1 = fmaf(w01.w, __builtin_amdgcn_rcpf(__builtin_amdgcn_exp2f(x1) + 1.0f), a1);
          float x2 = hi.x + w23.x;
          a2 = fmaf(w23.y, __builtin_amdgcn_rcpf(__builtin_amdgcn_exp2f(x2) + 1.0f), a2);
          float x3 = hi.y + w23.z;
          a3 = fmaf(w23.w, __builtin_amdgcn_rcpf(__builtin_amdgcn_exp2f(x3) + 1.0f), a3);
        }
        cur = nxt;
      }
      float e = Vs + ((a0 + a1) + (a2 + a3));
      e_f[bb8 * 256 + an] = e;
      float pe = __builtin_amdgcn_exp2f(K1 * e);
      #pragma unroll
      for (int off = 32; off >= 1; off >>= 1) pe += __shfl_xor(pe, off);
      if (lane == 0) Zpart[bb8][wv & 3] = pe;
    }
    __syncthreads();  // B3: e_f + Zpart ready

    // ---- softmax redistribution + xt (bf16) ----
    {
      const int b8s = tid >> 7;
      const int nn0 = (tid & 127) * 2;
      f4v zp = *(const f4v*)&Zpart[b8s][0];
      float zi = 1.0f / ((zp.x + zp.y) + (zp.z + zp.w));
      float2 ee = *(const float2*)&e_f[b8s * 256 + nn0];
      float p0 = __builtin_amdgcn_exp2f(K1 * ee.x);
      float p1 = __builtin_amdgcn_exp2f(K1 * ee.y);
      unsigned int packed = (unsigned int)f2bf(p0 * zi * ee.x)
                          | ((unsigned int)f2bf(p1 * zi * ee.y) << 16);
      *(unsigned int*)&xt_b[b8s * 264 + nn0] = packed;
    }
    __syncthreads();  // B4: xt ready

    // ---- xt-part of gates ----
    #pragma unroll
    for (int kp = 0; kp < 4; kp++) {
      const int k0 = kp * 2, k1 = kp * 2 + 1;
      s8v aA = *(const s8v*)&xt_b[l15 * 264 + k0 * 32 + quad * 8];
      s8v aB = *(const s8v*)&xt_b[l15 * 264 + k1 * 32 + quad * 8];
      const int r0 = (wv * 16 + l15) * 256;
      s8v b00 = *(const s8v*)&Wih_b[(size_t)(     0 + r0) + k0 * 32 + quad * 8];
      s8v b01 = *(const s8v*)&Wih_b[(size_t)( 65536 + r0) + k0 * 32 + quad * 8];
      s8v b02 = *(const s8v*)&Wih_b[(size_t)(131072 + r0) + k0 * 32 + quad * 8];
      s8v b03 = *(const s8v*)&Wih_b[(size_t)(196608 + r0) + k0 * 32 + quad * 8];
      s8v b10 = *(const s8v*)&Wih_b[(size_t)(     0 + r0) + k1 * 32 + quad * 8];
      s8v b11 = *(const s8v*)&Wih_b[(size_t)( 65536 + r0) + k1 * 32 + quad * 8];
      s8v b12 = *(const s8v*)&Wih_b[(size_t)(131072 + r0) + k1 * 32 + quad * 8];
      s8v b13 = *(const s8v*)&Wih_b[(size_t)(196608 + r0) + k1 * 32 + quad * 8];
      ga0 = MFMA16(aA, b00, ga0); ga1 = MFMA16(aA, b01, ga1);
      ga2 = MFMA16(aA, b02, ga2); ga3 = MFMA16(aA, b03, ga3);
      ga0 = MFMA16(aB, b10, ga0); ga1 = MFMA16(aB, b11, ga1);
      ga2 = MFMA16(aB, b12, ga2); ga3 = MFMA16(aB, b13, ga3);
    }

    // ---- pointwise LSTM straight from accumulators (lanes 0..31) ----
    if (lane < 32) {
      const int jj = wv * 16 + l15;
      #pragma unroll
      for (int r = 0; r < 4; r++) {
        const int m = quad * 4 + r;
        float iG = ga0[r] + bsum[jj];
        float fG = ga1[r] + bsum[256 + jj];
        float gG = ga2[r] + bsum[512 + jj];
        float oG = ga3[r] + bsum[768 + jj];
        float si = __builtin_amdgcn_rcpf(1.0f + __builtin_amdgcn_exp2f(-K1 * iG));
        float sf = __builtin_amdgcn_rcpf(1.0f + __builtin_amdgcn_exp2f(-K1 * fG));
        float so = __builtin_amdgcn_rcpf(1.0f + __builtin_amdgcn_exp2f(-K1 * oG));
        float tg_ = 1.0f - 2.0f * __builtin_amdgcn_rcpf(1.0f + __builtin_amdgcn_exp2f(K2 * gG));
        float cn = sf * c_f[m * 256 + jj] + si * tg_;
        float th = 1.0f - 2.0f * __builtin_amdgcn_rcpf(1.0f + __builtin_amdgcn_exp2f(K2 * cn));
        float hn = so * th;
        c_f[m * 256 + jj] = cn;
        c_b[m * 264 + jj] = f2bf(cn);
        h_b[m * 264 + jj] = f2bf(hn);
        h_hist[(m * 256 + jj) * 20 + (s & 15)] = f2bf(hn);
      }
    }

    // ---- full-line coalesced output dump every 16 steps (plain stores:
    //      L2 write-back merges the 4x16B into whole 64B lines, no RMW) ----
    if ((s & 15) == 15) {
      __syncthreads();
      #pragma unroll
      for (int p = 0; p < 2; p++) {
        int rid = p * 1024 + tid;
        int mB = rid >> 8, j = rid & 255;
        const us4* hp = (const us4*)&h_hist[rid * 20];
        float* dst = &out[(((size_t)blk * 8 + mB) * 256 + j) * 128 + (s - 15)];
        #pragma unroll
        for (int c = 0; c < 4; c++) {
          us4 u = hp[c];
          f4v o = { bfu(u.x), bfu(u.y), bfu(u.z), bfu(u.w) };
          *(f4v*)(dst + c * 4) = o;
        }
      }
    }
  }
}

extern "C" void kernel_launch(void* const* d_in, const int* in_sizes, int n_in,
                              void* d_out, int out_size, void* d_ws, size_t ws_size,
                              hipStream_t stream) {
  const float* x   = (const float*)d_in[0];
  const float* We  = (const float*)d_in[1];
  const float* Ue  = (const float*)d_in[2];
  const float* Ve  = (const float*)d_in[3];
  const float* Wih = (const float*)d_in[4];
  const float* Whh = (const float*)d_in[5];
  const float* bih = (const float*)d_in[6];
  const float* bhh = (const float*)d_in[7];
  float* out = (float*)d_out;

  char* p = (char*)d_ws;
  unsigned char*  UxK8  = (unsigned char*)p;  p += (size_t)67108864; // 2048*256*128 fp8
  unsigned short* Wih_b = (unsigned short*)p; p += 524288;
  unsigned short* Whh_b = (unsigned short*)p; p += 524288;
  unsigned short* We_b  = (unsigned short*)p; p += 131072;
  unsigned short* Ue_b  = (unsigned short*)p; p += 32768;
  float* bsum = (float*)p;

  prep_kernel<<<512, 256, 0, stream>>>(We, Ue, Wih, Whh, bih, bhh,
                                       Wih_b, Whh_b, We_b, Ue_b, bsum);
  ux_kernel<<<8192, 256, 0, stream>>>(x, Ue_b, UxK8);
  rnn_kernel<<<256, 1024, 0, stream>>>(UxK8, We_b, Wih_b, Whh_b, bsum, Ve, out);
}